// Round 1
// baseline (111.769 us; speedup 1.0000x reference)
//
#include <hip/hip_runtime.h>

#define NN 4096
#define DIN 512
#define DH 128
#define NH 4

typedef float f32x4 __attribute__((ext_vector_type(4)));
typedef _Float16 f16x8 __attribute__((ext_vector_type(8)));
typedef _Float16 f16x4 __attribute__((ext_vector_type(4)));

__device__ __forceinline__ float leaky(float x){ return x > 0.f ? x : 0.2f*x; }

// K1: featsT[h][e][i] = sum_d X[i][d]*Kw[h][d][e]  (f16 out) + a_s/a_n row dots
__global__ __launch_bounds__(256) void k_gemm1(
    const float* __restrict__ X, const float* __restrict__ Kw,
    const float* __restrict__ attn_s, const float* __restrict__ attn_n,
    _Float16* __restrict__ featsT, float* __restrict__ a_s, float* __restrict__ a_n)
{
  const int it = blockIdx.x, h = blockIdx.y;
  const int i0 = it*64;
  const int t = threadIdx.x, w = t>>6, lane = t&63;
  const int eoff = (w>>1)*64, ioff = (w&1)*32;
  const int lg = lane>>4, li = lane&15;

  __shared__ _Float16 KT[128][40];   // [e][d] pad 40 (2-way free)
  __shared__ _Float16 XT[64][40];    // [i][d]
  __shared__ float red_s[2][2][2][16];
  __shared__ float red_n[2][2][2][16];

  f32x4 acc[4][2] = {};

  for (int ks=0; ks<16; ++ks){
    const int d0 = ks*32;
    __syncthreads();
    // stage KT[e][d] = Kw[h][d0+d][e]; each task: 4 d for one e (coalesced over e)
    #pragma unroll
    for (int q=0;q<4;q++){
      int f = t + 256*q;
      int e = f & 127, dg = (f>>7)*4;
      f16x4 hv;
      #pragma unroll
      for (int k=0;k<4;k++)
        hv[k] = (_Float16)Kw[(h*DIN + d0 + dg + k)*DH + e];
      *(f16x4*)&KT[e][dg] = hv;
    }
    // stage XT[i][d] = X[i0+i][d0+d]
    #pragma unroll
    for (int q=0;q<2;q++){
      int f = t + 256*q;
      int i = f>>3, s = (f&7)*4;
      f32x4 v = *(const f32x4*)&X[(i0+i)*DIN + d0 + s];
      f16x4 hv; hv[0]=(_Float16)v[0]; hv[1]=(_Float16)v[1];
      hv[2]=(_Float16)v[2]; hv[3]=(_Float16)v[3];
      *(f16x4*)&XT[i][s] = hv;
    }
    __syncthreads();
    f16x8 af[4], bf[2];
    #pragma unroll
    for (int ef=0; ef<4; ++ef) af[ef] = *(const f16x8*)&KT[eoff + ef*16 + li][lg*8];
    #pragma unroll
    for (int f2=0; f2<2; ++f2) bf[f2] = *(const f16x8*)&XT[ioff + f2*16 + li][lg*8];
    #pragma unroll
    for (int ef=0; ef<4; ++ef)
      #pragma unroll
      for (int f2=0; f2<2; ++f2)
        acc[ef][f2] = __builtin_amdgcn_mfma_f32_16x16x32_f16(af[ef], bf[f2], acc[ef][f2], 0,0,0);
  }

  float ps[2] = {0,0}, pn[2] = {0,0};
  #pragma unroll
  for (int ef=0; ef<4; ++ef){
    #pragma unroll
    for (int r=0;r<4;r++){
      int e = eoff + ef*16 + lg*4 + r;
      float as_e = attn_s[h*DH + e];
      float an_e = attn_n[h*DH + e];
      #pragma unroll
      for (int f2=0; f2<2; ++f2){
        int irow = i0 + ioff + f2*16 + li;
        float v = acc[ef][f2][r];
        featsT[(h*DH + e)*NN + irow] = (_Float16)v;
        ps[f2] += v*as_e; pn[f2] += v*an_e;
      }
    }
  }
  #pragma unroll
  for (int f2=0; f2<2; ++f2){
    ps[f2] += __shfl_xor(ps[f2], 16); ps[f2] += __shfl_xor(ps[f2], 32);
    pn[f2] += __shfl_xor(pn[f2], 16); pn[f2] += __shfl_xor(pn[f2], 32);
  }
  if (lane < 16){
    red_s[w>>1][w&1][0][lane] = ps[0]; red_s[w>>1][w&1][1][lane] = ps[1];
    red_n[w>>1][w&1][0][lane] = pn[0]; red_n[w>>1][w&1][1][lane] = pn[1];
  }
  __syncthreads();
  if (t < 64){
    int ih = t>>5, fb = (t>>4)&1, l2 = t&15;
    a_s[h*NN + i0 + t] = red_s[0][ih][fb][l2] + red_s[1][ih][fb][l2];
    a_n[h*NN + i0 + t] = red_n[0][ih][fb][l2] + red_n[1][ih][fb][l2];
  }
}

// K2: Amax[h] = max_j a_n[h][j]
__global__ void k_amax(const float* __restrict__ a_n, float* __restrict__ Amax){
  int h = blockIdx.x, t = threadIdx.x;
  float m = -3.4e38f;
  for (int i=t; i<NN; i+=256) m = fmaxf(m, a_n[h*NN+i]);
  #pragma unroll
  for (int s=1; s<64; s<<=1) m = fmaxf(m, __shfl_xor(m, s));
  __shared__ float sm[4];
  if ((t&63)==0) sm[t>>6] = m;
  __syncthreads();
  if (t==0) Amax[h] = fmaxf(fmaxf(sm[0],sm[1]), fmaxf(sm[2],sm[3]));
}

// K3: per (64-row i-tile, 1024-col j-chunk): W = exp(leaky(as+an)-m)*adj on the fly,
// acc += W @ featsT_tile via MFMA. 8 waves = 4 heads x 2 row-halves.
__global__ __launch_bounds__(512) void k_pv(
    const float* __restrict__ adj, const _Float16* __restrict__ featsT,
    const float* __restrict__ a_s, const float* __restrict__ a_n,
    const float* __restrict__ Amax,
    _Float16* __restrict__ Opart, float* __restrict__ Dpart)
{
  const int it = blockIdx.x, jc = blockIdx.y;
  const int i0 = it*64, j0 = jc*1024;
  const int t = threadIdx.x, w = t>>6, lane = t&63;
  const int h = w&3, ihalf = w>>2;
  const int lg = lane>>4, li = lane&15, jb = lg*8;

  __shared__ float as_s[4][64];
  __shared__ float m_s[4][64];
  __shared__ float adj_s[64][36];          // pad 36: 2-way free on frag reads
  __shared__ _Float16 ft_s[4][128][40];    // [h][e][j] pad 40

  if (t < 256){
    int h2 = t>>6, i = t&63;
    float av = a_s[h2*NN + i0 + i];
    as_s[h2][i] = av;
    m_s[h2][i] = leaky(av + Amax[h2]);
  }

  f32x4 acc[2][8] = {};
  float dsum0 = 0.f, dsum1 = 0.f;

  for (int js=0; js<32; ++js){
    const int j = j0 + js*32;
    __syncthreads();
    {
      int row = t>>3, c4 = (t&7)*4;
      *(f32x4*)&adj_s[row][c4] = *(const f32x4*)&adj[(size_t)(i0+row)*NN + j + c4];
    }
    #pragma unroll
    for (int q=0;q<4;q++){
      int c = t + 512*q;
      int he = c>>2, seg = c&3;
      *(f32x4*)((_Float16*)ft_s + he*40 + seg*8) =
          *(const f32x4*)(featsT + (size_t)he*NN + j + seg*8);
    }
    __syncthreads();

    f32x4 an0 = *(const f32x4*)&a_n[h*NN + j + jb];
    f32x4 an1 = *(const f32x4*)&a_n[h*NN + j + jb + 4];
    f16x8 af[2];
    #pragma unroll
    for (int mi=0; mi<2; ++mi){
      int il = ihalf*32 + mi*16 + li;
      float asv = as_s[h][il], mv = m_s[h][il];
      f32x4 ad0 = *(const f32x4*)&adj_s[il][jb];
      f32x4 ad1 = *(const f32x4*)&adj_s[il][jb+4];
      float dacc = 0.f;
      f16x8 a;
      #pragma unroll
      for (int jj=0; jj<8; ++jj){
        float adv = (jj<4) ? ad0[jj] : ad1[jj-4];
        float anv = (jj<4) ? an0[jj] : an1[jj-4];
        float x = asv + anv;
        float l = x > 0.f ? x : 0.2f*x;
        float wv = (adv > 0.5f) ? __builtin_exp2f((l - mv)*1.44269504f) : 0.f;
        dacc += wv;
        a[jj] = (_Float16)wv;
      }
      if (mi==0) dsum0 += dacc; else dsum1 += dacc;
      af[mi] = a;
    }
    #pragma unroll
    for (int ef=0; ef<8; ++ef){
      f16x8 bfr = *(const f16x8*)((const _Float16*)ft_s + (h*DH + ef*16 + li)*40 + jb);
      acc[0][ef] = __builtin_amdgcn_mfma_f32_16x16x32_f16(af[0], bfr, acc[0][ef], 0,0,0);
      acc[1][ef] = __builtin_amdgcn_mfma_f32_16x16x32_f16(af[1], bfr, acc[1][ef], 0,0,0);
    }
  }

  dsum0 += __shfl_xor(dsum0,16); dsum0 += __shfl_xor(dsum0,32);
  dsum1 += __shfl_xor(dsum1,16); dsum1 += __shfl_xor(dsum1,32);
  const int chb = (jc*4 + h)*NN;
  if (lane < 16){
    Dpart[chb + i0 + ihalf*32 + lane] = dsum0;
    Dpart[chb + i0 + ihalf*32 + 16 + lane] = dsum1;
  }
  #pragma unroll
  for (int mi=0; mi<2; ++mi)
    #pragma unroll
    for (int ef=0; ef<8; ++ef)
      #pragma unroll
      for (int r=0;r<4;r++){
        int irow = i0 + ihalf*32 + mi*16 + lg*4 + r;
        int e = ef*16 + li;
        Opart[(size_t)(chb + irow)*DH + e] = (_Float16)acc[mi][ef][r];
      }
}

// K4: out[i][h*128+e] = sum_jc Opart / sum_jc Dpart + bias
__global__ __launch_bounds__(256) void k_out(
    const _Float16* __restrict__ Opart, const float* __restrict__ Dpart,
    const float* __restrict__ bias, float* __restrict__ out)
{
  int gid = blockIdx.x*256 + threadIdx.x;
  int base = gid*4;
  int i = base >> 9;
  int he = base & 511;
  int h = he >> 7;
  int e = he & 127;
  float n0=0,n1=0,n2=0,n3=0, den=0;
  #pragma unroll
  for (int jc=0; jc<4; ++jc){
    int ch = (jc*4+h)*NN + i;
    f16x4 v = *(const f16x4*)(Opart + (size_t)ch*DH + e);
    n0 += (float)v[0]; n1 += (float)v[1]; n2 += (float)v[2]; n3 += (float)v[3];
    den += Dpart[ch];
  }
  float inv = 1.f/den;
  f32x4 b4 = *(const f32x4*)&bias[he];
  f32x4 o; o[0]=n0*inv+b4[0]; o[1]=n1*inv+b4[1]; o[2]=n2*inv+b4[2]; o[3]=n3*inv+b4[3];
  *(f32x4*)&out[base] = o;
}

extern "C" void kernel_launch(void* const* d_in, const int* in_sizes, int n_in,
                              void* d_out, int out_size, void* d_ws, size_t ws_size,
                              hipStream_t stream)
{
  const float* adj   = (const float*)d_in[0];
  const float* X     = (const float*)d_in[1];
  const float* Kw    = (const float*)d_in[2];
  const float* bias  = (const float*)d_in[3];
  const float* atn_s = (const float*)d_in[4];
  const float* atn_n = (const float*)d_in[5];
  float* out = (float*)d_out;

  char* ws = (char*)d_ws;
  _Float16* featsT = (_Float16*)ws;                    // 4 MB
  float* a_s  = (float*)(ws + (size_t)4*1024*1024);    // 64 KB
  float* a_n  = a_s + NH*NN;                           // 64 KB
  float* Amax = a_n + NH*NN;                           // 256 B slot
  float* Dpart = Amax + 64;                            // 256 KB
  _Float16* Opart = (_Float16*)(Dpart + 4*NH*NN);      // 16 MB

  hipLaunchKernelGGL(k_gemm1, dim3(64,4), dim3(256), 0, stream,
                     X, Kw, atn_s, atn_n, featsT, a_s, a_n);
  hipLaunchKernelGGL(k_amax, dim3(4), dim3(256), 0, stream, a_n, Amax);
  hipLaunchKernelGGL(k_pv, dim3(64,4), dim3(512), 0, stream,
                     adj, featsT, a_s, a_n, Amax, Opart, Dpart);
  hipLaunchKernelGGL(k_out, dim3(2048), dim3(256), 0, stream,
                     Opart, Dpart, bias, out);
}

// Round 3
// 85.360 us; speedup vs baseline: 1.3094x; 1.3094x over previous
//
#include <hip/hip_runtime.h>

#define NN 4096
#define DIN 512
#define DH 128
#define NH 4

typedef float f32x4 __attribute__((ext_vector_type(4)));
typedef _Float16 f16x8 __attribute__((ext_vector_type(8)));
typedef _Float16 f16x4 __attribute__((ext_vector_type(4)));

__device__ __forceinline__ float leaky(float x){ return x > 0.f ? x : 0.2f*x; }

// K0: pack adjacency (0/1 f32) into bitmask, 32 cols per u32 word
__global__ __launch_bounds__(256) void k_pack(
    const float* __restrict__ adj, unsigned int* __restrict__ bmg)
{
  int tId = blockIdx.x*256 + threadIdx.x;     // 0 .. N*N/32-1
  const float* p = adj + (size_t)tId*32;
  unsigned int b = 0;
  #pragma unroll
  for (int k=0;k<8;k++){
    f32x4 v = *(const f32x4*)(p + k*4);
    #pragma unroll
    for (int q=0;q<4;q++) b |= (v[q] > 0.5f) ? (1u << (k*4+q)) : 0u;
  }
  bmg[tId] = b;
}

// K1: featsT[h][e][i] = sum_d X[i][d]*Kw[h][d][e]  (f16 out) + a_s/a_n row dots
__global__ __launch_bounds__(256) void k_gemm1(
    const float* __restrict__ X, const float* __restrict__ Kw,
    const float* __restrict__ attn_s, const float* __restrict__ attn_n,
    _Float16* __restrict__ featsT, float* __restrict__ a_s, float* __restrict__ a_n)
{
  const int it = blockIdx.x, h = blockIdx.y;
  const int i0 = it*64;
  const int t = threadIdx.x, w = t>>6, lane = t&63;
  const int eoff = (w>>1)*64, ioff = (w&1)*32;
  const int lg = lane>>4, li = lane&15;

  __shared__ _Float16 KT[128][40];
  __shared__ _Float16 XT[64][40];
  __shared__ float red_s[2][2][2][16];
  __shared__ float red_n[2][2][2][16];

  f32x4 acc[4][2] = {};

  for (int ks=0; ks<16; ++ks){
    const int d0 = ks*32;
    __syncthreads();
    #pragma unroll
    for (int q=0;q<4;q++){
      int f = t + 256*q;
      int e = f & 127, dg = (f>>7)*4;
      f16x4 hv;
      #pragma unroll
      for (int k=0;k<4;k++)
        hv[k] = (_Float16)Kw[(h*DIN + d0 + dg + k)*DH + e];
      *(f16x4*)&KT[e][dg] = hv;
    }
    #pragma unroll
    for (int q=0;q<2;q++){
      int f = t + 256*q;
      int i = f>>3, s = (f&7)*4;
      f32x4 v = *(const f32x4*)&X[(i0+i)*DIN + d0 + s];
      f16x4 hv; hv[0]=(_Float16)v[0]; hv[1]=(_Float16)v[1];
      hv[2]=(_Float16)v[2]; hv[3]=(_Float16)v[3];
      *(f16x4*)&XT[i][s] = hv;
    }
    __syncthreads();
    f16x8 af[4], bf[2];
    #pragma unroll
    for (int ef=0; ef<4; ++ef) af[ef] = *(const f16x8*)&KT[eoff + ef*16 + li][lg*8];
    #pragma unroll
    for (int f2=0; f2<2; ++f2) bf[f2] = *(const f16x8*)&XT[ioff + f2*16 + li][lg*8];
    #pragma unroll
    for (int ef=0; ef<4; ++ef)
      #pragma unroll
      for (int f2=0; f2<2; ++f2)
        acc[ef][f2] = __builtin_amdgcn_mfma_f32_16x16x32_f16(af[ef], bf[f2], acc[ef][f2], 0,0,0);
  }

  float ps[2] = {0,0}, pn[2] = {0,0};
  #pragma unroll
  for (int ef=0; ef<4; ++ef){
    #pragma unroll
    for (int r=0;r<4;r++){
      int e = eoff + ef*16 + lg*4 + r;
      float as_e = attn_s[h*DH + e];
      float an_e = attn_n[h*DH + e];
      #pragma unroll
      for (int f2=0; f2<2; ++f2){
        int irow = i0 + ioff + f2*16 + li;
        float v = acc[ef][f2][r];
        featsT[(h*DH + e)*NN + irow] = (_Float16)v;
        ps[f2] += v*as_e; pn[f2] += v*an_e;
      }
    }
  }
  #pragma unroll
  for (int f2=0; f2<2; ++f2){
    ps[f2] += __shfl_xor(ps[f2], 16); ps[f2] += __shfl_xor(ps[f2], 32);
    pn[f2] += __shfl_xor(pn[f2], 16); pn[f2] += __shfl_xor(pn[f2], 32);
  }
  if (lane < 16){
    red_s[w>>1][w&1][0][lane] = ps[0]; red_s[w>>1][w&1][1][lane] = ps[1];
    red_n[w>>1][w&1][0][lane] = pn[0]; red_n[w>>1][w&1][1][lane] = pn[1];
  }
  __syncthreads();
  if (t < 64){
    int ih = t>>5, fb = (t>>4)&1, l2 = t&15;
    a_s[h*NN + i0 + t] = red_s[0][ih][fb][l2] + red_s[1][ih][fb][l2];
    a_n[h*NN + i0 + t] = red_n[0][ih][fb][l2] + red_n[1][ih][fb][l2];
  }
}

// K2: Amax[h] = max_j a_n[h][j]
__global__ void k_amax(const float* __restrict__ a_n, float* __restrict__ Amax){
  int h = blockIdx.x, t = threadIdx.x;
  float m = -3.4e38f;
  for (int i=t; i<NN; i+=256) m = fmaxf(m, a_n[h*NN+i]);
  #pragma unroll
  for (int s=1; s<64; s<<=1) m = fmaxf(m, __shfl_xor(m, s));
  __shared__ float sm[4];
  if ((t&63)==0) sm[t>>6] = m;
  __syncthreads();
  if (t==0) Amax[h] = fmaxf(fmaxf(sm[0],sm[1]), fmaxf(sm[2],sm[3]));
}

// K3: single-head blocks; 8 waves x 16 rows; j-chunk 1024 in 32-col steps.
// bitmask + a_n staged once; featsT staged 8KB/step via global_load_lds.
__global__ __launch_bounds__(512, 4) void k_pv(
    const unsigned int* __restrict__ bmg, const _Float16* __restrict__ featsT,
    const float* __restrict__ a_s, const float* __restrict__ a_n,
    const float* __restrict__ Amax,
    _Float16* __restrict__ Opart, float* __restrict__ Dpart)
{
  const int it = blockIdx.x, h = blockIdx.y, jcI = blockIdx.z;
  const int i0 = it*128, j0 = jcI*1024;
  const int t = threadIdx.x, w = t>>6, lane = t&63;
  const int lg = lane>>4, li = lane&15;

  __shared__ _Float16 ft[128*32];            // [e][32 j] 8 KB, stride 64B (uniform banks)
  __shared__ float an_s[1024];               // 4 KB
  __shared__ unsigned char bm_s[128*144];    // rows padded to 144B (2-way = free)

  if (t < 256) *(f32x4*)&an_s[t*4] = *(const f32x4*)&a_n[h*NN + j0 + t*4];
  #pragma unroll
  for (int p=0;p<2;p++){
    int rr = p*64 + (t>>3), c = t&7;
    uint4 v = *(const uint4*)((const char*)bmg + (size_t)(i0+rr)*(NN/8) + jcI*128 + c*16);
    *(uint4*)&bm_s[rr*144 + c*16] = v;
  }
  // per-lane row constants (A-frag row = li within this wave's 16-row group)
  const int rowA = i0 + w*16 + li;
  const float asv = a_s[h*NN + rowA];
  const float mv = leaky(asv + Amax[h]);
  const float negmc = -mv * 1.44269504f;
  __syncthreads();

  f32x4 acc[8] = {};
  f32x4 accd = {};
  f16x8 ones;
  #pragma unroll
  for (int q=0;q<8;q++) ones[q] = (_Float16)1.0f;

  const int e_st = t>>2, c_st = t&3;
  const size_t src_row = (size_t)(h*DH + e_st)*NN + j0 + c_st*8;

  for (int js=0; js<32; ++js){
    __syncthreads();   // prior ft reads done
    __builtin_amdgcn_global_load_lds(
        (const __attribute__((address_space(1))) void*)(featsT + src_row + js*32),
        (__attribute__((address_space(3))) void*)(&ft[t*8]),
        16, 0, 0);

    const int jb = js*32 + lg*8;
    f32x4 an0 = *(const f32x4*)&an_s[jb];
    f32x4 an1 = *(const f32x4*)&an_s[jb+4];
    unsigned int byte = bm_s[(w*16+li)*144 + js*4 + lg];
    f16x8 af;
    #pragma unroll
    for (int q=0;q<8;q++){
      float anv = (q<4) ? an0[q] : an1[q-4];
      float x = asv + anv;
      float l = fmaxf(x, 0.2f*x);
      float e2 = __builtin_exp2f(fmaf(l, 1.44269504f, negmc));
      float wv = (byte & (1u<<q)) ? e2 : 0.f;
      af[q] = (_Float16)wv;
    }
    __syncthreads();   // ft staged (vmcnt drained at barrier)
    #pragma unroll
    for (int ef=0; ef<8; ++ef){
      f16x8 bfr = *(const f16x8*)&ft[(ef*16+li)*32 + lg*8];
      acc[ef] = __builtin_amdgcn_mfma_f32_16x16x32_f16(af, bfr, acc[ef], 0,0,0);
    }
    accd = __builtin_amdgcn_mfma_f32_16x16x32_f16(af, ones, accd, 0,0,0);
  }

  const size_t chb = (size_t)(jcI*4 + h)*NN;
  if (li == 0)
    *(f32x4*)&Dpart[chb + i0 + w*16 + lg*4] = accd;   // reg r <-> row lg*4+r
  #pragma unroll
  for (int ef=0; ef<8; ++ef)
    #pragma unroll
    for (int r=0;r<4;r++){
      int row = i0 + w*16 + lg*4 + r;
      Opart[(chb + row)*DH + ef*16 + li] = (_Float16)acc[ef][r];
    }
}

// K4: out[i][h*128+e] = sum_jc Opart / sum_jc Dpart + bias
__global__ __launch_bounds__(256) void k_out(
    const _Float16* __restrict__ Opart, const float* __restrict__ Dpart,
    const float* __restrict__ bias, float* __restrict__ out)
{
  int gid = blockIdx.x*256 + threadIdx.x;
  int base = gid*4;
  int i = base >> 9;
  int he = base & 511;
  int h = he >> 7;
  int e = he & 127;
  float n0=0,n1=0,n2=0,n3=0, den=0;
  #pragma unroll
  for (int jc=0; jc<4; ++jc){
    int ch = (jc*4+h)*NN + i;
    f16x4 v = *(const f16x4*)(Opart + (size_t)ch*DH + e);
    n0 += (float)v[0]; n1 += (float)v[1]; n2 += (float)v[2]; n3 += (float)v[3];
    den += Dpart[ch];
  }
  float inv = 1.f/den;
  f32x4 b4 = *(const f32x4*)&bias[he];
  f32x4 o; o[0]=n0*inv+b4[0]; o[1]=n1*inv+b4[1]; o[2]=n2*inv+b4[2]; o[3]=n3*inv+b4[3];
  *(f32x4*)&out[base] = o;
}

extern "C" void kernel_launch(void* const* d_in, const int* in_sizes, int n_in,
                              void* d_out, int out_size, void* d_ws, size_t ws_size,
                              hipStream_t stream)
{
  const float* adj   = (const float*)d_in[0];
  const float* X     = (const float*)d_in[1];
  const float* Kw    = (const float*)d_in[2];
  const float* bias  = (const float*)d_in[3];
  const float* atn_s = (const float*)d_in[4];
  const float* atn_n = (const float*)d_in[5];
  float* out = (float*)d_out;

  char* ws = (char*)d_ws;
  _Float16* featsT = (_Float16*)ws;                            // 4 MB
  unsigned int* bmg = (unsigned int*)(ws + ((size_t)4<<20));   // 2 MB
  float* a_s  = (float*)(ws + (size_t)6*1024*1024);            // 64 KB
  float* a_n  = a_s + NH*NN;                                   // 64 KB
  float* Amax = a_n + NH*NN;                                   // 256 B slot
  float* Dpart = Amax + 64;                                    // 256 KB
  _Float16* Opart = (_Float16*)(Dpart + 4*NH*NN);              // 16 MB

  hipLaunchKernelGGL(k_pack, dim3(2048), dim3(256), 0, stream, adj, bmg);
  hipLaunchKernelGGL(k_gemm1, dim3(64,4), dim3(256), 0, stream,
                     X, Kw, atn_s, atn_n, featsT, a_s, a_n);
  hipLaunchKernelGGL(k_amax, dim3(4), dim3(256), 0, stream, a_n, Amax);
  hipLaunchKernelGGL(k_pv, dim3(32,4,4), dim3(512), 0, stream,
                     bmg, featsT, a_s, a_n, Amax, Opart, Dpart);
  hipLaunchKernelGGL(k_out, dim3(2048), dim3(256), 0, stream,
                     Opart, Dpart, bias, out);
}

// Round 6
// 73.008 us; speedup vs baseline: 1.5309x; 1.1692x over previous
//
#include <hip/hip_runtime.h>

#define NN 4096
#define DIN 512
#define DH 128
#define NH 4
#define L2E 1.44269504f

typedef float f32x4 __attribute__((ext_vector_type(4)));
typedef _Float16 f16x8 __attribute__((ext_vector_type(8)));
typedef _Float16 f16x4 __attribute__((ext_vector_type(4)));

__device__ __forceinline__ float leaky(float x){ return x > 0.f ? x : 0.2f*x; }

// K0: pack adjacency (0/1 f32) into bitmask, 32 cols per u32 word
__global__ __launch_bounds__(256) void k_pack(
    const float* __restrict__ adj, unsigned int* __restrict__ bmg)
{
  int tId = blockIdx.x*256 + threadIdx.x;
  const float* p = adj + (size_t)tId*32;
  unsigned int b = 0;
  #pragma unroll
  for (int k=0;k<8;k++){
    f32x4 v = *(const f32x4*)(p + k*4);
    #pragma unroll
    for (int q=0;q<4;q++) b |= (v[q] > 0.5f) ? (1u << (k*4+q)) : 0u;
  }
  bmg[tId] = b;
}

// K1: featsT[h][e][i] = sum_d X[i][d]*Kw[h][d][e]  (f16 out) + a_s/a_n row dots
__global__ __launch_bounds__(256) void k_gemm1(
    const float* __restrict__ X, const float* __restrict__ Kw,
    const float* __restrict__ attn_s, const float* __restrict__ attn_n,
    _Float16* __restrict__ featsT, float* __restrict__ a_s, float* __restrict__ a_n)
{
  const int it = blockIdx.x, h = blockIdx.y;
  const int i0 = it*64;
  const int t = threadIdx.x, w = t>>6, lane = t&63;
  const int eoff = (w>>1)*64, ioff = (w&1)*32;
  const int lg = lane>>4, li = lane&15;

  __shared__ _Float16 KT[128][40];
  __shared__ _Float16 XT[64][40];
  __shared__ float red_s[2][2][2][16];
  __shared__ float red_n[2][2][2][16];

  f32x4 acc[4][2] = {};

  for (int ks=0; ks<16; ++ks){
    const int d0 = ks*32;
    __syncthreads();
    #pragma unroll
    for (int q=0;q<4;q++){
      int f = t + 256*q;
      int e = f & 127, dg = (f>>7)*4;
      f16x4 hv;
      #pragma unroll
      for (int k=0;k<4;k++)
        hv[k] = (_Float16)Kw[(h*DIN + d0 + dg + k)*DH + e];
      *(f16x4*)&KT[e][dg] = hv;
    }
    #pragma unroll
    for (int q=0;q<2;q++){
      int f = t + 256*q;
      int i = f>>3, s = (f&7)*4;
      f32x4 v = *(const f32x4*)&X[(i0+i)*DIN + d0 + s];
      f16x4 hv; hv[0]=(_Float16)v[0]; hv[1]=(_Float16)v[1];
      hv[2]=(_Float16)v[2]; hv[3]=(_Float16)v[3];
      *(f16x4*)&XT[i][s] = hv;
    }
    __syncthreads();
    f16x8 af[4], bf[2];
    #pragma unroll
    for (int ef=0; ef<4; ++ef) af[ef] = *(const f16x8*)&KT[eoff + ef*16 + li][lg*8];
    #pragma unroll
    for (int f2=0; f2<2; ++f2) bf[f2] = *(const f16x8*)&XT[ioff + f2*16 + li][lg*8];
    #pragma unroll
    for (int ef=0; ef<4; ++ef)
      #pragma unroll
      for (int f2=0; f2<2; ++f2)
        acc[ef][f2] = __builtin_amdgcn_mfma_f32_16x16x32_f16(af[ef], bf[f2], acc[ef][f2], 0,0,0);
  }

  float ps[2] = {0,0}, pn[2] = {0,0};
  #pragma unroll
  for (int ef=0; ef<4; ++ef){
    #pragma unroll
    for (int r=0;r<4;r++){
      int e = eoff + ef*16 + lg*4 + r;
      float as_e = attn_s[h*DH + e];
      float an_e = attn_n[h*DH + e];
      #pragma unroll
      for (int f2=0; f2<2; ++f2){
        int irow = i0 + ioff + f2*16 + li;
        float v = acc[ef][f2][r];
        featsT[(h*DH + e)*NN + irow] = (_Float16)v;
        ps[f2] += v*as_e; pn[f2] += v*an_e;
      }
    }
  }
  #pragma unroll
  for (int f2=0; f2<2; ++f2){
    ps[f2] += __shfl_xor(ps[f2], 16); ps[f2] += __shfl_xor(ps[f2], 32);
    pn[f2] += __shfl_xor(pn[f2], 16); pn[f2] += __shfl_xor(pn[f2], 32);
  }
  if (lane < 16){
    red_s[w>>1][w&1][0][lane] = ps[0]; red_s[w>>1][w&1][1][lane] = ps[1];
    red_n[w>>1][w&1][0][lane] = pn[0]; red_n[w>>1][w&1][1][lane] = pn[1];
  }
  __syncthreads();
  if (t < 64){
    int ih = t>>5, fb = (t>>4)&1, l2 = t&15;
    a_s[h*NN + i0 + t] = red_s[0][ih][fb][l2] + red_s[1][ih][fb][l2];
    a_n[h*NN + i0 + t] = red_n[0][ih][fb][l2] + red_n[1][ih][fb][l2];
  }
}

// K2: Amax[h] = max_j a_n[h][j]; EA=exp(an), GA=exp(0.2*an) tables (f32)
__global__ void k_amax(const float* __restrict__ a_n, float* __restrict__ Amax,
                       float* __restrict__ EA_g, float* __restrict__ GA_g){
  int h = blockIdx.x, t = threadIdx.x;
  float m = -3.4e38f;
  for (int i=t; i<NN; i+=256){
    float v = a_n[h*NN+i];
    m = fmaxf(m, v);
    EA_g[h*NN+i] = __builtin_exp2f(v*L2E);
    GA_g[h*NN+i] = __builtin_exp2f(0.2f*v*L2E);
  }
  #pragma unroll
  for (int s=1; s<64; s<<=1) m = fmaxf(m, __shfl_xor(m, s));
  __shared__ float sm[4];
  if ((t&63)==0) sm[t>>6] = m;
  __syncthreads();
  if (t==0) Amax[h] = fmaxf(fmaxf(sm[0],sm[1]), fmaxf(sm[2],sm[3]));
}

// K3: 4 waves x 32 rows (2 A-frags); double-buffered ft with XOR-swizzled slots;
// W = max(Ei*EA[j], Gi*GA[j]) & adjacency-bit  (exact factorization of exp(leaky))
__global__ __launch_bounds__(256, 3) void k_pv(
    const unsigned int* __restrict__ bmg, const _Float16* __restrict__ featsT,
    const float* __restrict__ a_s, const float* __restrict__ Amax,
    const float* __restrict__ EA_g, const float* __restrict__ GA_g,
    _Float16* __restrict__ Opart, float* __restrict__ Dpart)
{
  const int it = blockIdx.x, h = blockIdx.y, jcI = blockIdx.z;
  const int i0 = it*128, j0 = jcI*1024;
  const int t = threadIdx.x, w = t>>6, lane = t&63;
  const int lg = lane>>4, li = lane&15;

  __shared__ _Float16 ft[2][128*32];        // 2 x 8 KB, slot-swizzled
  __shared__ float EA_s[1024], GA_s[1024];  // 8 KB
  __shared__ unsigned char bm_s[128*144];   // 18 KB, 144B rows (16B-aligned, 2-way free)

  // one-time staging
  __builtin_amdgcn_global_load_lds(
      (const __attribute__((address_space(1))) void*)(EA_g + h*NN + j0 + t*4),
      (__attribute__((address_space(3))) void*)(&EA_s[t*4]), 16, 0, 0);
  __builtin_amdgcn_global_load_lds(
      (const __attribute__((address_space(1))) void*)(GA_g + h*NN + j0 + t*4),
      (__attribute__((address_space(3))) void*)(&GA_s[t*4]), 16, 0, 0);
  // full bitmask: 128 rows x 128 bytes = 1024 uint4 loads (4 per thread)
  #pragma unroll
  for (int p=0;p<4;p++){
    int idx = p*256 + t;
    int r = idx>>3, c = idx&7;
    uint4 v = *(const uint4*)((const char*)bmg + (size_t)(i0+r)*(NN/8) + jcI*128 + c*16);
    *(uint4*)&bm_s[r*144 + c*16] = v;
  }

  // per-lane row constants (2 row groups)
  const int r0 = w*32 + li, r1 = r0 + 16;
  const float am = Amax[h];
  const float as0 = a_s[h*NN + i0 + r0];
  const float as1 = a_s[h*NN + i0 + r1];
  const float m0 = leaky(as0 + am), m1 = leaky(as1 + am);
  const float E0 = __builtin_exp2f((as0 - m0)*L2E);
  const float G0 = __builtin_exp2f((0.2f*as0 - m0)*L2E);
  const float E1 = __builtin_exp2f((as1 - m1)*L2E);
  const float G1 = __builtin_exp2f((0.2f*as1 - m1)*L2E);

  // ft staging: linear LDS dest, source slot pre-swizzled (l = p ^ ((r>>1)&3))
  auto STAGE = [&](int buf, int js){
    #pragma unroll
    for (int q=0;q<2;q++){
      int idx = q*256 + t;
      int r = idx>>2, p = idx&3;
      int l = p ^ ((r>>1)&3);
      __builtin_amdgcn_global_load_lds(
          (const __attribute__((address_space(1))) void*)(featsT + (size_t)(h*DH + r)*NN + j0 + js*32 + l*8),
          (__attribute__((address_space(3))) void*)(&ft[buf][idx*8]), 16, 0, 0);
    }
  };

  STAGE(0, 0);
  __syncthreads();

  f32x4 acc0[8] = {}, acc1[8] = {};
  f32x4 accd0 = {}, accd1 = {};
  f16x8 ones;
  #pragma unroll
  for (int q=0;q<8;q++) ones[q] = (_Float16)1.0f;

  const int slot = lg ^ ((li>>1)&3);        // read-side swizzle

  for (int js=0; js<32; ++js){
    const int cur = js&1;
    if (js < 31) STAGE(cur^1, js+1);

    const int jb = js*32 + lg*8;
    f32x4 ea0 = *(const f32x4*)&EA_s[jb];
    f32x4 ea1 = *(const f32x4*)&EA_s[jb+4];
    f32x4 ga0 = *(const f32x4*)&GA_s[jb];
    f32x4 ga1 = *(const f32x4*)&GA_s[jb+4];
    unsigned int b0 = bm_s[r0*144 + js*4 + lg];
    unsigned int b1 = bm_s[r1*144 + js*4 + lg];

    f16x8 af0, af1;
    #pragma unroll
    for (int q=0;q<8;q++){
      float ev = (q<4) ? ea0[q] : ea1[q-4];
      float gv = (q<4) ? ga0[q] : ga1[q-4];
      float w0 = fmaxf(E0*ev, G0*gv);
      float w1 = fmaxf(E1*ev, G1*gv);
      unsigned mq0 = (unsigned)(((int)(b0 << (31-q))) >> 31);
      unsigned mq1 = (unsigned)(((int)(b1 << (31-q))) >> 31);
      w0 = __builtin_bit_cast(float, __builtin_bit_cast(unsigned, w0) & mq0);
      w1 = __builtin_bit_cast(float, __builtin_bit_cast(unsigned, w1) & mq1);
      af0[q] = (_Float16)w0;
      af1[q] = (_Float16)w1;
    }

    #pragma unroll
    for (int ef=0; ef<8; ++ef){
      f16x8 bfr = *(const f16x8*)&ft[cur][(ef*16+li)*32 + slot*8];
      acc0[ef] = __builtin_amdgcn_mfma_f32_16x16x32_f16(af0, bfr, acc0[ef], 0,0,0);
      acc1[ef] = __builtin_amdgcn_mfma_f32_16x16x32_f16(af1, bfr, acc1[ef], 0,0,0);
    }
    accd0 = __builtin_amdgcn_mfma_f32_16x16x32_f16(af0, ones, accd0, 0,0,0);
    accd1 = __builtin_amdgcn_mfma_f32_16x16x32_f16(af1, ones, accd1, 0,0,0);

    __syncthreads();   // drains vmcnt (next buf staged) + lgkm (reads done)
  }

  const size_t chb = (size_t)(jcI*4 + h)*NN;
  if (li == 0){
    *(f32x4*)&Dpart[chb + i0 + w*32 + lg*4] = accd0;
    *(f32x4*)&Dpart[chb + i0 + w*32 + 16 + lg*4] = accd1;
  }
  #pragma unroll
  for (int ef=0; ef<8; ++ef)
    #pragma unroll
    for (int r=0;r<4;r++){
      int row0 = i0 + w*32 + lg*4 + r;
      Opart[(chb + row0)*DH + ef*16 + li] = (_Float16)acc0[ef][r];
      Opart[(chb + row0 + 16)*DH + ef*16 + li] = (_Float16)acc1[ef][r];
    }
}

// K4: out[i][h*128+e] = sum_jc Opart / sum_jc Dpart + bias
__global__ __launch_bounds__(256) void k_out(
    const _Float16* __restrict__ Opart, const float* __restrict__ Dpart,
    const float* __restrict__ bias, float* __restrict__ out)
{
  int gid = blockIdx.x*256 + threadIdx.x;
  int base = gid*4;
  int i = base >> 9;
  int he = base & 511;
  int h = he >> 7;
  int e = he & 127;
  float n0=0,n1=0,n2=0,n3=0, den=0;
  #pragma unroll
  for (int jc=0; jc<4; ++jc){
    int ch = (jc*4+h)*NN + i;
    f16x4 v = *(const f16x4*)(Opart + (size_t)ch*DH + e);
    n0 += (float)v[0]; n1 += (float)v[1]; n2 += (float)v[2]; n3 += (float)v[3];
    den += Dpart[ch];
  }
  float inv = 1.f/den;
  f32x4 b4 = *(const f32x4*)&bias[he];
  f32x4 o; o[0]=n0*inv+b4[0]; o[1]=n1*inv+b4[1]; o[2]=n2*inv+b4[2]; o[3]=n3*inv+b4[3];
  *(f32x4*)&out[base] = o;
}

extern "C" void kernel_launch(void* const* d_in, const int* in_sizes, int n_in,
                              void* d_out, int out_size, void* d_ws, size_t ws_size,
                              hipStream_t stream)
{
  const float* adj   = (const float*)d_in[0];
  const float* X     = (const float*)d_in[1];
  const float* Kw    = (const float*)d_in[2];
  const float* bias  = (const float*)d_in[3];
  const float* atn_s = (const float*)d_in[4];
  const float* atn_n = (const float*)d_in[5];
  float* out = (float*)d_out;

  char* ws = (char*)d_ws;
  _Float16* featsT = (_Float16*)ws;                            // 4 MB
  unsigned int* bmg = (unsigned int*)(ws + ((size_t)4<<20));   // 2 MB
  float* a_s  = (float*)(ws + (size_t)6*1024*1024);            // 64 KB
  float* a_n  = a_s + NH*NN;                                   // 64 KB
  float* Amax = a_n + NH*NN;                                   // 256 B slot
  float* EA_g = Amax + 64;                                     // 64 KB
  float* GA_g = EA_g + NH*NN;                                  // 64 KB
  float* Dpart = GA_g + NH*NN;                                 // 256 KB
  _Float16* Opart = (_Float16*)(Dpart + 4*NH*NN);              // 16 MB

  hipLaunchKernelGGL(k_pack, dim3(2048), dim3(256), 0, stream, adj, bmg);
  hipLaunchKernelGGL(k_gemm1, dim3(64,4), dim3(256), 0, stream,
                     X, Kw, atn_s, atn_n, featsT, a_s, a_n);
  hipLaunchKernelGGL(k_amax, dim3(4), dim3(256), 0, stream, a_n, Amax, EA_g, GA_g);
  hipLaunchKernelGGL(k_pv, dim3(32,4,4), dim3(256), 0, stream,
                     bmg, featsT, a_s, Amax, EA_g, GA_g, Opart, Dpart);
  hipLaunchKernelGGL(k_out, dim3(2048), dim3(256), 0, stream,
                     Opart, Dpart, bias, out);
}